// Round 1
// baseline (121.074 us; speedup 1.0000x reference)
//
#include <hip/hip_runtime.h>

#define G 5000
#define K 256
#define BATCH 16
#define HID 64
#define STEPS 10
#define NC 250          // gene chunks: 250 * 20 == 5000 exactly
#define GPER 20

// ---------------------------------------------------------------------------
// Kernel A: partial max-pool. 250 blocks = 250 chunks of 20 genes; each block
// now computes ALL 16 batches so every M row is fetched from HBM exactly once
// (the old 2-blocks-per-chunk layout read M twice, and the harness's 256 MiB
// workspace poison leaves L3 cold every iteration, so both reads were HBM).
// partials[c][b][k] = max_{g in chunk c} t[b,g] * M[g,k];  t,M >= 0 so 0 is a
// valid identity. Side job: warm A into L3 (each block pulls 1KB) so the appnp
// kernel's 16 blocks x 256KB A-preload hits Infinity Cache, not HBM.
// ---------------------------------------------------------------------------
__global__ void maxpool_kernel(const float* __restrict__ t,
                               const float* __restrict__ M,
                               const float* __restrict__ A,
                               float* __restrict__ partials,
                               float* __restrict__ awarm) {
    __shared__ float tl[GPER][BATCH];    // t values for this chunk x 16 batches
    const int c  = blockIdx.x;           // chunk 0..249
    const int k  = threadIdx.x;          // 0..255
    const int g0 = c * GPER;

    // ---- A-warm: 64 lanes pull one float4 each (1KB/block, ~full A overall)
    float4 aw = make_float4(0.f, 0.f, 0.f, 0.f);
    if (k < 64)
        aw = ((const float4*)A)[((size_t)blockIdx.x * 64 + k) & 16383];

    // ---- stage t[0..15, g0..g0+19] into LDS
    for (int i = k; i < GPER * BATCH; i += 256) {
        int gi = i >> 4, b = i & 15;
        tl[gi][b] = t[b * G + g0 + gi];
    }
    __syncthreads();

    float mx[BATCH];
#pragma unroll
    for (int b = 0; b < BATCH; ++b) mx[b] = 0.f;

#pragma unroll 4
    for (int gi = 0; gi < GPER; ++gi) {
        float mg = M[(size_t)(g0 + gi) * K + k];   // coalesced across k, read ONCE
#pragma unroll
        for (int b = 0; b < BATCH; ++b)
            mx[b] = fmaxf(mx[b], tl[gi][b] * mg);  // LDS broadcast
    }
#pragma unroll
    for (int b = 0; b < BATCH; ++b)
        partials[((size_t)c * BATCH + b) * K + k] = mx[b];

    // keep the A-warm loads alive (64 garbage floats in ws, raced by blocks)
    if (k < 64) awarm[k] = aw.x + aw.y + aw.z + aw.w;
}

// ---------------------------------------------------------------------------
// Kernel B: full APPNP chain, ONE dispatch, A-STATIONARY IN REGISTERS
// (round-3 structure — standalone kernel so Areg[64] stays in VGPRs; the
// fused variants spilled it to scratch, R4/R5 post-mortem). One block per
// batch row; thread (k, jc) owns A[jc*64..+63, k] in 64 VGPRs.
// Only change this round: chunk-reduce bounds adapt to NC=250.
// ---------------------------------------------------------------------------
__global__ __launch_bounds__(1024, 4)
void appnp_fused(const float* __restrict__ partials,
                 const float* __restrict__ A,
                 const int* __restrict__ cell_idx,
                 const float* __restrict__ cell_emb,
                 const float* __restrict__ W2,
                 const float* __restrict__ b2,
                 float* __restrict__ Zfin,
                 float* __restrict__ ce_dot) {
    __shared__ float4 zb[2][K / 4];      // double-buffered Z row
    __shared__ float  Sm[K];
    __shared__ float  red[4][K];
    __shared__ float  ce_red[HID];

    const int b  = blockIdx.x;
    const int t  = threadIdx.x;
    const int k  = t & 255;
    const int jc = t >> 8;               // 0..3, wave-uniform
    const int j0 = jc * 64;

    // ---- preload this thread's A column-slice into registers (L3-warm) ----
    float Areg[64];
#pragma unroll
    for (int jj = 0; jj < 64; ++jj)
        Areg[jj] = A[(size_t)(j0 + jj) * K + k];     // coalesced across k

    // ---- reduce partials over the 250 chunks (4-way split over jc) ----
    {
        const int CPJ = (NC + 3) / 4;                // 63
        int c0 = jc * CPJ, c1 = min(NC, c0 + CPJ);
        float m = 0.f;
        for (int c = c0; c < c1; ++c)
            m = fmaxf(m, partials[((size_t)c * BATCH + b) * K + k]);
        red[jc][k] = m;
    }
    if (t < HID) {
        int ci = cell_idx[b];
        ce_red[t] = cell_emb[ci * HID + t] * W2[t];
    }
    __syncthreads();
    if (jc == 0) {
        float s = fmaxf(fmaxf(red[0][k], red[1][k]), fmaxf(red[2][k], red[3][k]));
        Sm[k] = s;
        ((float*)zb)[k] = s;             // zb[0] = Z0
    }
    if (t == 0) {
        float s = b2[0];
        for (int h = 0; h < HID; ++h) s += ce_red[h];
        ce_dot[b] = s;
    }
    __syncthreads();

    // ---- 10 propagation steps, LDS+register only ----
    for (int s = 0; s < STEPS; ++s) {
        const float4* cur4 = zb[s & 1] + (j0 >> 2);
        float*        nxt  = (float*)zb[(s + 1) & 1];
        float acc = 0.f;
#pragma unroll
        for (int q = 0; q < 16; ++q) {
            float4 c4 = cur4[q];                     // wave-uniform LDS broadcast
            acc = fmaf(c4.x, Areg[4 * q + 0], acc);
            acc = fmaf(c4.y, Areg[4 * q + 1], acc);
            acc = fmaf(c4.z, Areg[4 * q + 2], acc);
            acc = fmaf(c4.w, Areg[4 * q + 3], acc);
        }
        red[jc][k] = acc;
        __syncthreads();
        if (jc == 0)
            nxt[k] = 0.9f * (red[0][k] + red[1][k] + red[2][k] + red[3][k])
                   + 0.1f * Sm[k];
        __syncthreads();
    }
    // after 10 (even) steps the result sits in zb[0]
    if (jc == 0) Zfin[b * K + k] = ((float*)zb)[k];
}

// ---------------------------------------------------------------------------
// Kernel C: z_gene = Z @ M^T fused with the per-element MLP.
// This round: the Z reads are wave-uniform (index depends only on batch-group
// and k4), so they move OFF the LDS pipe onto the SCALAR pipe — bg is forced
// into an SGPR via readfirstlane and Z is read through a uniform global
// pointer (compiler emits s_load_dwordx4). The old 16 KB zl staging + barrier
// are gone; the LDS pipe keeps only the small wpack/w2l broadcasts, and the
// K-dot inner loop becomes VALU-bound (16 FMA per 1 coalesced M float4).
// ---------------------------------------------------------------------------
__global__ void final_kernel(const float* __restrict__ ctl,
                             const float* __restrict__ t_in,
                             const float* __restrict__ Z,
                             const float* __restrict__ M,
                             const float* __restrict__ W1,
                             const float* __restrict__ b1,
                             const float* __restrict__ W2,
                             const float* __restrict__ ce_dot,
                             float* __restrict__ out) {
    __shared__ float4 wpack[HID];            // (W1row0, W1row1, W1row2, b1)
    __shared__ float  w2l[HID];
    __shared__ float  cel[BATCH];

    const int t = threadIdx.x;
    if (t < HID) {
        wpack[t] = make_float4(W1[t], W1[HID + t], W1[2 * HID + t], b1[t]);
        w2l[t] = W2[t];
    }
    if (t < BATCH) cel[t] = ce_dot[t];
    __syncthreads();

    const int gl = t & 63;
    const int bg = __builtin_amdgcn_readfirstlane(t >> 6);  // wave-uniform SGPR
    const int g  = blockIdx.x * 64 + gl;
    if (g >= G) return;

    // uniform base pointer -> scalar loads on the SMEM pipe
    const float4* Zw = (const float4*)(Z + (size_t)bg * 4 * K);

    float acc[4] = {0.f, 0.f, 0.f, 0.f};
    const float4* M4 = (const float4*)(M + (size_t)g * K);
#pragma unroll 4
    for (int k4 = 0; k4 < K / 4; ++k4) {
        float4 m4 = M4[k4];                          // coalesced b128 across gl
#pragma unroll
        for (int i = 0; i < 4; ++i) {
            float4 z4 = Zw[i * (K / 4) + k4];        // uniform -> s_load_dwordx4
            acc[i] = fmaf(m4.x, z4.x, acc[i]);
            acc[i] = fmaf(m4.y, z4.y, acc[i]);
            acc[i] = fmaf(m4.z, z4.z, acc[i]);
            acc[i] = fmaf(m4.w, z4.w, acc[i]);
        }
    }

    float cv[4], tv[4], y[4];
#pragma unroll
    for (int i = 0; i < 4; ++i) {
        int b = bg * 4 + i;
        cv[i] = ctl[b * G + g];        // coalesced across gl
        tv[i] = t_in[b * G + g];
        y[i] = cel[b];
    }
#pragma unroll 4
    for (int h = 0; h < HID; ++h) {
        float4 w = wpack[h];           // LDS broadcast (only LDS user now)
        float w2h = w2l[h];
#pragma unroll
        for (int i = 0; i < 4; ++i) {
            float pre = w.w;
            pre = fmaf(cv[i], w.x, pre);
            pre = fmaf(tv[i], w.y, pre);
            pre = fmaf(acc[i], w.z, pre);
            pre = fmaxf(pre, 0.f);
            y[i] = fmaf(pre, w2h, y[i]);
        }
    }
#pragma unroll
    for (int i = 0; i < 4; ++i)
        out[(bg * 4 + i) * G + g] = y[i];
}

// ---------------------------------------------------------------------------
extern "C" void kernel_launch(void* const* d_in, const int* in_sizes, int n_in,
                              void* d_out, int out_size, void* d_ws, size_t ws_size,
                              hipStream_t stream) {
    const float* ctl      = (const float*)d_in[0];
    const float* tgt      = (const float*)d_in[1];
    const int*   cell_idx = (const int*)d_in[2];
    // d_in[3] = drug_fp (unused by the reference output)
    const float* M        = (const float*)d_in[4];
    const float* A        = (const float*)d_in[5];
    const float* W1       = (const float*)d_in[6];
    const float* b1       = (const float*)d_in[7];
    const float* cell_emb = (const float*)d_in[8];
    const float* W2       = (const float*)d_in[9];
    const float* b2       = (const float*)d_in[10];
    float* out = (float*)d_out;

    float* partials = (float*)d_ws;                     // 250*16*256 f32 (4 MB)
    float* Zfin  = partials + (size_t)NC * BATCH * K;   // 16*256
    float* ce    = Zfin + BATCH * K;                    // 16
    float* awarm = ce + BATCH;                          // 64 (garbage dump)

    maxpool_kernel<<<NC, 256, 0, stream>>>(tgt, M, A, partials, awarm);
    appnp_fused<<<BATCH, 1024, 0, stream>>>(partials, A, cell_idx, cell_emb,
                                            W2, b2, Zfin, ce);
    final_kernel<<<(G + 63) / 64, 256, 0, stream>>>(ctl, tgt, Zfin, M, W1, b1,
                                                    W2, ce, out);
}

// Round 2
// 114.810 us; speedup vs baseline: 1.0546x; 1.0546x over previous
//
#include <hip/hip_runtime.h>

#define G 5000
#define K 256
#define BATCH 16
#define HID 64
#define STEPS 10
#define NC 125          // gene chunks: 125 * 40 == 5000 exactly
#define GPER 40

// ---------------------------------------------------------------------------
// Kernel A: partial max-pool. 125 blocks = 125 chunks of 40 genes; each block
// computes ALL 16 batches so every M row is fetched from HBM exactly once
// (5 MB instead of round-0's 10 MB; the 256 MiB harness poison leaves L3 cold
// every iteration so M always comes from HBM here). NC stays at 125 so kernel
// B's chunk-reduce keeps its round-0 (measured-good) cost.
// partials[c][b][k] = max_{g in chunk c} t[b,g] * M[g,k];  t,M >= 0 so 0 is a
// valid identity. Side job: warm A into L3 (each block pulls 2 KB) so the
// appnp kernel's 16 blocks x 256KB A-preload hits Infinity Cache, not HBM.
// ---------------------------------------------------------------------------
__global__ void maxpool_kernel(const float* __restrict__ t,
                               const float* __restrict__ M,
                               const float* __restrict__ A,
                               float* __restrict__ partials,
                               float* __restrict__ awarm) {
    __shared__ float tl[GPER][BATCH];    // t values for this chunk x 16 batches
    const int c  = blockIdx.x;           // chunk 0..124
    const int k  = threadIdx.x;          // 0..255
    const int g0 = c * GPER;

    // ---- A-warm: 128 lanes pull one float4 each (2KB/block, ~all of A)
    float4 aw = make_float4(0.f, 0.f, 0.f, 0.f);
    if (k < 128)
        aw = ((const float4*)A)[((size_t)blockIdx.x * 128 + k) & 16383];

    // ---- stage t[0..15, g0..g0+39] into LDS
    for (int i = k; i < GPER * BATCH; i += 256) {
        int gi = i >> 4, b = i & 15;
        tl[gi][b] = t[b * G + g0 + gi];
    }
    __syncthreads();

    float mx[BATCH];
#pragma unroll
    for (int b = 0; b < BATCH; ++b) mx[b] = 0.f;

#pragma unroll 4
    for (int gi = 0; gi < GPER; ++gi) {
        float mg = M[(size_t)(g0 + gi) * K + k];   // coalesced across k, read ONCE
#pragma unroll
        for (int b = 0; b < BATCH; ++b)
            mx[b] = fmaxf(mx[b], tl[gi][b] * mg);  // LDS broadcast
    }
#pragma unroll
    for (int b = 0; b < BATCH; ++b)
        partials[((size_t)c * BATCH + b) * K + k] = mx[b];

    // keep the A-warm loads alive (garbage floats in ws, raced by blocks)
    if (k < 128) awarm[k & 63] = aw.x + aw.y + aw.z + aw.w;
}

// ---------------------------------------------------------------------------
// Kernel B: full APPNP chain, ONE dispatch, A-STATIONARY IN REGISTERS
// (round-3 structure — standalone kernel so Areg[64] stays in VGPRs; the
// fused variants spilled it to scratch, R4/R5 post-mortem). One block per
// batch row; thread (k, jc) owns A[jc*64..+63, k] in 64 VGPRs.
// New this round: the chunk-reduce is VECTORIZED — threads remap to
// (k4 in [0,64) float4-lane, cg in [0,16) chunk-group); each thread issues
// only 7-8 independent float4 loads (vs 32 scalar) for the same 2 MB, then a
// 16-way LDS combine. The latency-bound phase at 16-block occupancy shrinks.
// ---------------------------------------------------------------------------
__global__ __launch_bounds__(1024, 4)
void appnp_fused(const float* __restrict__ partials,
                 const float* __restrict__ A,
                 const int* __restrict__ cell_idx,
                 const float* __restrict__ cell_emb,
                 const float* __restrict__ W2,
                 const float* __restrict__ b2,
                 float* __restrict__ Zfin,
                 float* __restrict__ ce_dot) {
    __shared__ float4 zb[2][K / 4];      // double-buffered Z row
    __shared__ float  Sm[K];
    __shared__ float  red[16][K];        // phase1: 16 c-group maxima; steps: rows 0..3
    __shared__ float  ce_red[HID];

    const int b  = blockIdx.x;
    const int t  = threadIdx.x;
    const int k  = t & 255;
    const int jc = t >> 8;               // 0..3, wave-uniform
    const int j0 = jc * 64;

    // ---- preload this thread's A column-slice into registers (L3-warm) ----
    float Areg[64];
#pragma unroll
    for (int jj = 0; jj < 64; ++jj)
        Areg[jj] = A[(size_t)(j0 + jj) * K + k];     // coalesced across k

    // ---- reduce partials over the 125 chunks: float4 loads, 16 c-groups ----
    {
        const int k4 = t & 63;           // float4 index within a k-row
        const int cg = t >> 6;           // chunk-group 0..15
        const float4* p4 = (const float4*)partials;
        float4 m4 = make_float4(0.f, 0.f, 0.f, 0.f);
        for (int c = cg; c < NC; c += 16) {          // 7-8 independent 16B loads
            float4 v = p4[((size_t)c * BATCH + b) * (K / 4) + k4];
            m4.x = fmaxf(m4.x, v.x);
            m4.y = fmaxf(m4.y, v.y);
            m4.z = fmaxf(m4.z, v.z);
            m4.w = fmaxf(m4.w, v.w);
        }
        ((float4*)red[cg])[k4] = m4;
    }
    if (t < HID) {
        int ci = cell_idx[b];
        ce_red[t] = cell_emb[ci * HID + t] * W2[t];
    }
    __syncthreads();
    if (jc == 0) {                        // t == k in [0,256)
        float s = red[0][k];
#pragma unroll
        for (int cgi = 1; cgi < 16; ++cgi) s = fmaxf(s, red[cgi][k]);
        Sm[k] = s;
        ((float*)zb)[k] = s;             // zb[0] = Z0
    }
    if (t == 0) {
        float s = b2[0];
        for (int h = 0; h < HID; ++h) s += ce_red[h];
        ce_dot[b] = s;
    }
    __syncthreads();

    // ---- 10 propagation steps, LDS+register only ----
    for (int s = 0; s < STEPS; ++s) {
        const float4* cur4 = zb[s & 1] + (j0 >> 2);
        float*        nxt  = (float*)zb[(s + 1) & 1];
        float acc = 0.f;
#pragma unroll
        for (int q = 0; q < 16; ++q) {
            float4 c4 = cur4[q];                     // wave-uniform LDS broadcast
            acc = fmaf(c4.x, Areg[4 * q + 0], acc);
            acc = fmaf(c4.y, Areg[4 * q + 1], acc);
            acc = fmaf(c4.z, Areg[4 * q + 2], acc);
            acc = fmaf(c4.w, Areg[4 * q + 3], acc);
        }
        red[jc][k] = acc;
        __syncthreads();
        if (jc == 0)
            nxt[k] = 0.9f * (red[0][k] + red[1][k] + red[2][k] + red[3][k])
                   + 0.1f * Sm[k];
        __syncthreads();
    }
    // after 10 (even) steps the result sits in zb[0]
    if (jc == 0) Zfin[b * K + k] = ((float*)zb)[k];
}

// ---------------------------------------------------------------------------
// Kernel C: z_gene = Z @ M^T fused with the per-element MLP.
// Reverted to the round-0 LDS-staged version (measured good at 115 µs); the
// scalar-Z s_load variant regressed (long lgkm chains + scalar-cache thrash
// across 79 blocks reading the same 16 KB).
// ---------------------------------------------------------------------------
__global__ void final_kernel(const float* __restrict__ ctl,
                             const float* __restrict__ t_in,
                             const float* __restrict__ Z,
                             const float* __restrict__ M,
                             const float* __restrict__ W1,
                             const float* __restrict__ b1,
                             const float* __restrict__ W2,
                             const float* __restrict__ ce_dot,
                             float* __restrict__ out) {
    __shared__ float4 zl[BATCH * (K / 4)];   // 16 KB, Z rows as float4
    __shared__ float4 wpack[HID];            // (W1row0, W1row1, W1row2, b1)
    __shared__ float  w2l[HID];
    __shared__ float  cel[BATCH];

    const int t = threadIdx.x;
    const float4* Z4 = (const float4*)Z;
    for (int i = t; i < BATCH * (K / 4); i += 256) zl[i] = Z4[i];
    if (t < HID) {
        wpack[t] = make_float4(W1[t], W1[HID + t], W1[2 * HID + t], b1[t]);
        w2l[t] = W2[t];
    }
    if (t < BATCH) cel[t] = ce_dot[t];
    __syncthreads();

    const int gl = t & 63;
    const int bg = t >> 6;             // wave-uniform -> LDS broadcasts below
    const int g = blockIdx.x * 64 + gl;
    if (g >= G) return;

    float acc[4] = {0.f, 0.f, 0.f, 0.f};
    const float4* M4 = (const float4*)(M + (size_t)g * K);
#pragma unroll 4
    for (int k4 = 0; k4 < K / 4; ++k4) {
        float4 m4 = M4[k4];
#pragma unroll
        for (int i = 0; i < 4; ++i) {
            float4 z4 = zl[(bg * 4 + i) * (K / 4) + k4];   // broadcast read
            acc[i] = fmaf(m4.x, z4.x, acc[i]);
            acc[i] = fmaf(m4.y, z4.y, acc[i]);
            acc[i] = fmaf(m4.z, z4.z, acc[i]);
            acc[i] = fmaf(m4.w, z4.w, acc[i]);
        }
    }

    float cv[4], tv[4], y[4];
#pragma unroll
    for (int i = 0; i < 4; ++i) {
        int b = bg * 4 + i;
        cv[i] = ctl[b * G + g];        // coalesced across gl
        tv[i] = t_in[b * G + g];
        y[i] = cel[b];
    }
#pragma unroll 4
    for (int h = 0; h < HID; ++h) {
        float4 w = wpack[h];           // broadcast
        float w2h = w2l[h];
#pragma unroll
        for (int i = 0; i < 4; ++i) {
            float pre = w.w;
            pre = fmaf(cv[i], w.x, pre);
            pre = fmaf(tv[i], w.y, pre);
            pre = fmaf(acc[i], w.z, pre);
            pre = fmaxf(pre, 0.f);
            y[i] = fmaf(pre, w2h, y[i]);
        }
    }
#pragma unroll
    for (int i = 0; i < 4; ++i)
        out[(bg * 4 + i) * G + g] = y[i];
}

// ---------------------------------------------------------------------------
extern "C" void kernel_launch(void* const* d_in, const int* in_sizes, int n_in,
                              void* d_out, int out_size, void* d_ws, size_t ws_size,
                              hipStream_t stream) {
    const float* ctl      = (const float*)d_in[0];
    const float* tgt      = (const float*)d_in[1];
    const int*   cell_idx = (const int*)d_in[2];
    // d_in[3] = drug_fp (unused by the reference output)
    const float* M        = (const float*)d_in[4];
    const float* A        = (const float*)d_in[5];
    const float* W1       = (const float*)d_in[6];
    const float* b1       = (const float*)d_in[7];
    const float* cell_emb = (const float*)d_in[8];
    const float* W2       = (const float*)d_in[9];
    const float* b2       = (const float*)d_in[10];
    float* out = (float*)d_out;

    float* partials = (float*)d_ws;                     // 125*16*256 f32 (2 MB)
    float* Zfin  = partials + (size_t)NC * BATCH * K;   // 16*256
    float* ce    = Zfin + BATCH * K;                    // 16
    float* awarm = ce + BATCH;                          // 64 (garbage dump)

    maxpool_kernel<<<NC, 256, 0, stream>>>(tgt, M, A, partials, awarm);
    appnp_fused<<<BATCH, 1024, 0, stream>>>(partials, A, cell_idx, cell_emb,
                                            W2, b2, Zfin, ce);
    final_kernel<<<(G + 63) / 64, 256, 0, stream>>>(ctl, tgt, Zfin, M, W1, b1,
                                                    W2, ce, out);
}

// Round 3
// 107.182 us; speedup vs baseline: 1.1296x; 1.0712x over previous
//
#include <hip/hip_runtime.h>

#define G 5000
#define K 256
#define BATCH 16
#define HID 64
#define STEPS 10
#define NC 125          // gene chunks: 125 * 40 == 5000 exactly
#define GPER 40

// ---------------------------------------------------------------------------
// Kernel A: partial max-pool. 250 blocks = 125 chunks x 2 k-halves, so all
// ~250 CUs get a block (was 125). Each block: 40 genes x 16 batches x 128 k.
// M is still fetched from HBM exactly once (the two k-half blocks read
// disjoint halves of each row). The M column-slice is FULLY UNROLLED into
// mrow[40] VGPRs: 40 independent loads in flight -> one ~900cy cold-HBM epoch
// instead of ten (the old unroll-4 chain was ~3.7us at 1 wave/SIMD, no TLP).
// partials layout is unchanged so kernel B is untouched.
// Side job: warm A into L3 (1KB/block x 250 blocks ~ all of A) for kernel B.
// ---------------------------------------------------------------------------
__global__ __launch_bounds__(256)
void maxpool_kernel(const float* __restrict__ t,
                    const float* __restrict__ M,
                    const float* __restrict__ A,
                    float* __restrict__ partials,
                    float* __restrict__ awarm) {
    __shared__ float tl[GPER][BATCH];    // t values for this chunk x 16 batches
    const int c   = blockIdx.x >> 1;     // chunk 0..124
    const int kh  = blockIdx.x & 1;      // k-half 0..1
    const int tid = threadIdx.x;         // 0..255
    const int kl  = tid & 127;
    const int bg  = tid >> 7;            // 0..1 -> batches bg*8..+8 (wave-uniform)
    const int g0  = c * GPER;
    const int k   = kh * 128 + kl;       // column 0..255

    // ---- A-warm: 64 lanes pull one float4 each (1KB/block)
    float4 aw = make_float4(0.f, 0.f, 0.f, 0.f);
    if (tid < 64)
        aw = ((const float4*)A)[((size_t)blockIdx.x * 64 + tid) & 16383];

    // ---- stage t[0..15, g0..g0+39] into LDS
    for (int i = tid; i < GPER * BATCH; i += 256) {
        int gi = i >> 4, b = i & 15;
        tl[gi][b] = t[b * G + g0 + gi];
    }
    __syncthreads();

    // ---- full-unroll M column slice: 40 independent loads in flight ----
    float mrow[GPER];
#pragma unroll
    for (int gi = 0; gi < GPER; ++gi)
        mrow[gi] = M[(size_t)(g0 + gi) * K + k];   // coalesced across kl

    float mx[8];
#pragma unroll
    for (int b = 0; b < 8; ++b) mx[b] = 0.f;

#pragma unroll
    for (int gi = 0; gi < GPER; ++gi) {
#pragma unroll
        for (int b = 0; b < 8; ++b)
            mx[b] = fmaxf(mx[b], tl[gi][bg * 8 + b] * mrow[gi]);  // LDS broadcast
    }
#pragma unroll
    for (int b = 0; b < 8; ++b)
        partials[((size_t)c * BATCH + bg * 8 + b) * K + k] = mx[b];

    // keep the A-warm loads alive (garbage floats in ws, raced by blocks)
    if (tid < 64) awarm[tid] = aw.x + aw.y + aw.z + aw.w;
}

// ---------------------------------------------------------------------------
// Kernel B: full APPNP chain, ONE dispatch, A-STATIONARY IN REGISTERS
// (unchanged from round 2 — measured-good). One block per batch row; thread
// (k, jc) owns A[jc*64..+63, k] in 64 VGPRs. Chunk-reduce is vectorized:
// (k4, cg) remap, 7-8 independent float4 loads + 16-way LDS combine.
// ---------------------------------------------------------------------------
__global__ __launch_bounds__(1024, 4)
void appnp_fused(const float* __restrict__ partials,
                 const float* __restrict__ A,
                 const int* __restrict__ cell_idx,
                 const float* __restrict__ cell_emb,
                 const float* __restrict__ W2,
                 const float* __restrict__ b2,
                 float* __restrict__ Zfin,
                 float* __restrict__ ce_dot) {
    __shared__ float4 zb[2][K / 4];      // double-buffered Z row
    __shared__ float  Sm[K];
    __shared__ float  red[16][K];        // phase1: 16 c-group maxima; steps: rows 0..3
    __shared__ float  ce_red[HID];

    const int b  = blockIdx.x;
    const int t  = threadIdx.x;
    const int k  = t & 255;
    const int jc = t >> 8;               // 0..3, wave-uniform
    const int j0 = jc * 64;

    // ---- preload this thread's A column-slice into registers (L3-warm) ----
    float Areg[64];
#pragma unroll
    for (int jj = 0; jj < 64; ++jj)
        Areg[jj] = A[(size_t)(j0 + jj) * K + k];     // coalesced across k

    // ---- reduce partials over the 125 chunks: float4 loads, 16 c-groups ----
    {
        const int k4 = t & 63;           // float4 index within a k-row
        const int cg = t >> 6;           // chunk-group 0..15
        const float4* p4 = (const float4*)partials;
        float4 m4 = make_float4(0.f, 0.f, 0.f, 0.f);
        for (int c = cg; c < NC; c += 16) {          // 7-8 independent 16B loads
            float4 v = p4[((size_t)c * BATCH + b) * (K / 4) + k4];
            m4.x = fmaxf(m4.x, v.x);
            m4.y = fmaxf(m4.y, v.y);
            m4.z = fmaxf(m4.z, v.z);
            m4.w = fmaxf(m4.w, v.w);
        }
        ((float4*)red[cg])[k4] = m4;
    }
    if (t < HID) {
        int ci = cell_idx[b];
        ce_red[t] = cell_emb[ci * HID + t] * W2[t];
    }
    __syncthreads();
    if (jc == 0) {                        // t == k in [0,256)
        float s = red[0][k];
#pragma unroll
        for (int cgi = 1; cgi < 16; ++cgi) s = fmaxf(s, red[cgi][k]);
        Sm[k] = s;
        ((float*)zb)[k] = s;             // zb[0] = Z0
    }
    if (t == 0) {
        float s = b2[0];
        for (int h = 0; h < HID; ++h) s += ce_red[h];
        ce_dot[b] = s;
    }
    __syncthreads();

    // ---- 10 propagation steps, LDS+register only ----
    for (int s = 0; s < STEPS; ++s) {
        const float4* cur4 = zb[s & 1] + (j0 >> 2);
        float*        nxt  = (float*)zb[(s + 1) & 1];
        float acc = 0.f;
#pragma unroll
        for (int q = 0; q < 16; ++q) {
            float4 c4 = cur4[q];                     // wave-uniform LDS broadcast
            acc = fmaf(c4.x, Areg[4 * q + 0], acc);
            acc = fmaf(c4.y, Areg[4 * q + 1], acc);
            acc = fmaf(c4.z, Areg[4 * q + 2], acc);
            acc = fmaf(c4.w, Areg[4 * q + 3], acc);
        }
        red[jc][k] = acc;
        __syncthreads();
        if (jc == 0)
            nxt[k] = 0.9f * (red[0][k] + red[1][k] + red[2][k] + red[3][k])
                   + 0.1f * Sm[k];
        __syncthreads();
    }
    // after 10 (even) steps the result sits in zb[0]
    if (jc == 0) Zfin[b * K + k] = ((float*)zb)[k];
}

// ---------------------------------------------------------------------------
// Kernel C: z_gene = Z @ M^T fused with the per-element MLP.
// This round: (1) 158 blocks = 79 gene-groups x 2 batch-halves — per-thread
// work halves (acc[2], MLP VALU halves, per-CU LDS-pipe pressure halves) and
// ~158 CUs get a block instead of 79; (2) the M row walk is REGISTER
// DOUBLE-BUFFERED (8 chunks x 8 float4): the next chunk's 8 loads are issued
// before the current chunk's FMAs, hiding the ~500cy L3 latency that the old
// unroll-4 chain exposed 16x per thread at 1 wave/SIMD. M is L3-warm from
// kernel A, so the extra read by the second batch-half block is cheap.
// ---------------------------------------------------------------------------
__global__ __launch_bounds__(256)
void final_kernel(const float* __restrict__ ctl,
                  const float* __restrict__ t_in,
                  const float* __restrict__ Z,
                  const float* __restrict__ M,
                  const float* __restrict__ W1,
                  const float* __restrict__ b1,
                  const float* __restrict__ W2,
                  const float* __restrict__ ce_dot,
                  float* __restrict__ out) {
    __shared__ float4 zl[8 * (K / 4)];       // 8 KB: this half's 8 Z rows
    __shared__ float4 wpack[HID];            // (W1row0, W1row1, W1row2, b1)
    __shared__ float  w2l[HID];
    __shared__ float  cel[8];

    const int tid = threadIdx.x;
    const int bh  = blockIdx.x & 1;          // batch half: batches bh*8..+8
    const int gb  = blockIdx.x >> 1;         // gene group 0..78
    const int b0  = bh * 8;

    const float4* Z4 = (const float4*)Z + (size_t)b0 * (K / 4);
    for (int i = tid; i < 8 * (K / 4); i += 256) zl[i] = Z4[i];
    if (tid < HID) {
        wpack[tid] = make_float4(W1[tid], W1[HID + tid], W1[2 * HID + tid], b1[tid]);
        w2l[tid] = W2[tid];
    }
    if (tid < 8) cel[tid] = ce_dot[b0 + tid];
    __syncthreads();

    const int gl = tid & 63;
    const int bg = tid >> 6;             // 0..3 -> 2 batches each (wave-uniform)
    const int g  = gb * 64 + gl;
    if (g >= G) return;                  // no barriers after this point

    const float4* M4 = (const float4*)(M + (size_t)g * K);

    float acc0 = 0.f, acc1 = 0.f;
    float4 mc[8];
#pragma unroll
    for (int u = 0; u < 8; ++u) mc[u] = M4[u];          // chunk 0 in flight

#pragma unroll
    for (int kc = 0; kc < 8; ++kc) {
        float4 mn[8];
        if (kc < 7) {
#pragma unroll
            for (int u = 0; u < 8; ++u) mn[u] = M4[(kc + 1) * 8 + u];  // prefetch
        }
#pragma unroll
        for (int u = 0; u < 8; ++u) {
            const int k4 = kc * 8 + u;
            float4 m4 = mc[u];
            float4 za = zl[(bg * 2 + 0) * (K / 4) + k4];   // broadcast read
            float4 zc = zl[(bg * 2 + 1) * (K / 4) + k4];   // broadcast read
            acc0 = fmaf(m4.x, za.x, acc0);
            acc0 = fmaf(m4.y, za.y, acc0);
            acc0 = fmaf(m4.z, za.z, acc0);
            acc0 = fmaf(m4.w, za.w, acc0);
            acc1 = fmaf(m4.x, zc.x, acc1);
            acc1 = fmaf(m4.y, zc.y, acc1);
            acc1 = fmaf(m4.z, zc.z, acc1);
            acc1 = fmaf(m4.w, zc.w, acc1);
        }
        if (kc < 7) {
#pragma unroll
            for (int u = 0; u < 8; ++u) mc[u] = mn[u];  // SSA rename, no movs
        }
    }

    const int ba = b0 + bg * 2;
    const int bb = ba + 1;
    float cva = ctl[ba * G + g], cvb = ctl[bb * G + g];   // coalesced across gl
    float tva = t_in[ba * G + g], tvb = t_in[bb * G + g];
    float ya  = cel[bg * 2],      yb  = cel[bg * 2 + 1];
#pragma unroll 8
    for (int h = 0; h < HID; ++h) {
        float4 w = wpack[h];           // broadcast
        float w2h = w2l[h];
        float pa = fmaf(cva, w.x, fmaf(tva, w.y, fmaf(acc0, w.z, w.w)));
        pa = fmaxf(pa, 0.f);
        ya = fmaf(pa, w2h, ya);
        float pb = fmaf(cvb, w.x, fmaf(tvb, w.y, fmaf(acc1, w.z, w.w)));
        pb = fmaxf(pb, 0.f);
        yb = fmaf(pb, w2h, yb);
    }
    out[ba * G + g] = ya;
    out[bb * G + g] = yb;
}

// ---------------------------------------------------------------------------
extern "C" void kernel_launch(void* const* d_in, const int* in_sizes, int n_in,
                              void* d_out, int out_size, void* d_ws, size_t ws_size,
                              hipStream_t stream) {
    const float* ctl      = (const float*)d_in[0];
    const float* tgt      = (const float*)d_in[1];
    const int*   cell_idx = (const int*)d_in[2];
    // d_in[3] = drug_fp (unused by the reference output)
    const float* M        = (const float*)d_in[4];
    const float* A        = (const float*)d_in[5];
    const float* W1       = (const float*)d_in[6];
    const float* b1       = (const float*)d_in[7];
    const float* cell_emb = (const float*)d_in[8];
    const float* W2       = (const float*)d_in[9];
    const float* b2       = (const float*)d_in[10];
    float* out = (float*)d_out;

    float* partials = (float*)d_ws;                     // 125*16*256 f32 (2 MB)
    float* Zfin  = partials + (size_t)NC * BATCH * K;   // 16*256
    float* ce    = Zfin + BATCH * K;                    // 16
    float* awarm = ce + BATCH;                          // 64 (garbage dump)

    maxpool_kernel<<<NC * 2, 256, 0, stream>>>(tgt, M, A, partials, awarm);
    appnp_fused<<<BATCH, 1024, 0, stream>>>(partials, A, cell_idx, cell_emb,
                                            W2, b2, Zfin, ce);
    final_kernel<<<79 * 2, 256, 0, stream>>>(ctl, tgt, Zfin, M, W1, b1,
                                             W2, ce, out);
}

// Round 4
// 106.812 us; speedup vs baseline: 1.1335x; 1.0035x over previous
//
#include <hip/hip_runtime.h>

#define G 5000
#define K 256
#define BATCH 16
#define HID 64
#define STEPS 10
#define NC 125          // gene chunks: 125 * 40 == 5000 exactly
#define GPER 40

// ---------------------------------------------------------------------------
// Kernel A: partial max-pool (unchanged from round 3 — measured good).
// 250 blocks = 125 chunks x 2 k-halves; M column fully unrolled into
// mrow[40] VGPRs (one cold-HBM latency epoch); M read from HBM exactly once.
// Side job: warm A into L3 for kernel B's per-block 256KB A-preload.
// ---------------------------------------------------------------------------
__global__ __launch_bounds__(256)
void maxpool_kernel(const float* __restrict__ t,
                    const float* __restrict__ M,
                    const float* __restrict__ A,
                    float* __restrict__ partials,
                    float* __restrict__ awarm) {
    __shared__ float tl[GPER][BATCH];    // t values for this chunk x 16 batches
    const int c   = blockIdx.x >> 1;     // chunk 0..124
    const int kh  = blockIdx.x & 1;      // k-half 0..1
    const int tid = threadIdx.x;         // 0..255
    const int kl  = tid & 127;
    const int bg  = tid >> 7;            // 0..1 -> batches bg*8..+8 (wave-uniform)
    const int g0  = c * GPER;
    const int k   = kh * 128 + kl;       // column 0..255

    // ---- A-warm: 64 lanes pull one float4 each (1KB/block)
    float4 aw = make_float4(0.f, 0.f, 0.f, 0.f);
    if (tid < 64)
        aw = ((const float4*)A)[((size_t)blockIdx.x * 64 + tid) & 16383];

    // ---- stage t[0..15, g0..g0+39] into LDS
    for (int i = tid; i < GPER * BATCH; i += 256) {
        int gi = i >> 4, b = i & 15;
        tl[gi][b] = t[b * G + g0 + gi];
    }
    __syncthreads();

    // ---- full-unroll M column slice: 40 independent loads in flight ----
    float mrow[GPER];
#pragma unroll
    for (int gi = 0; gi < GPER; ++gi)
        mrow[gi] = M[(size_t)(g0 + gi) * K + k];   // coalesced across kl

    float mx[8];
#pragma unroll
    for (int b = 0; b < 8; ++b) mx[b] = 0.f;

#pragma unroll
    for (int gi = 0; gi < GPER; ++gi) {
#pragma unroll
        for (int b = 0; b < 8; ++b)
            mx[b] = fmaxf(mx[b], tl[gi][bg * 8 + b] * mrow[gi]);  // LDS broadcast
    }
#pragma unroll
    for (int b = 0; b < 8; ++b)
        partials[((size_t)c * BATCH + bg * 8 + b) * K + k] = mx[b];

    // keep the A-warm loads alive (garbage floats in ws, raced by blocks)
    if (tid < 64) awarm[tid] = aw.x + aw.y + aw.z + aw.w;
}

// ---------------------------------------------------------------------------
// Kernel B: APPNP chain, REDESIGNED for 4x less LDS-pipe pressure.
// Old structure: 1024 thr, 1 k-col x 64 j per thread -> 256 ds_read_b128
// wave-instrs per step through one LDS pipe (~3k cy/step, ~13us/10 steps).
// New: 512 thr = 8 waves; wave w owns j in [32w,32w+32) (WAVE-UNIFORM ->
// every z read is a same-address b128 broadcast); lane l owns k-quad 4l..4l+3
// with A[j0..j0+31][k0..k0+3] in 32 float4 VGPRs (128 regs, 2 waves/SIMD).
// Per step: 8 uniform z-reads feed 128 FMA (z reuse x4 in registers), 1
// partial ds_write_b128/wave, 256-thread combine (8 b32 reads + blend with
// Sm held in a REGISTER). DS/step ~650cy vs ~3100cy. Same 2 barriers/step.
// ---------------------------------------------------------------------------
__global__ __launch_bounds__(512, 2)
void appnp_fused(const float* __restrict__ partials,
                 const float* __restrict__ A,
                 const int* __restrict__ cell_idx,
                 const float* __restrict__ cell_emb,
                 const float* __restrict__ W2,
                 const float* __restrict__ b2,
                 float* __restrict__ Zfin,
                 float* __restrict__ ce_dot) {
    __shared__ float4 zb4[2][K / 4];     // double-buffered Z row (2 x 1KB)
    __shared__ float4 red4[8][K / 4];    // init: 8 c-group maxima; steps: 8 wave partials
    __shared__ float  ce_red[HID];

    const int b  = blockIdx.x;
    const int t  = threadIdx.x;
    const int l  = t & 63;
    const int w  = t >> 6;               // wave 0..7, uniform
    const int j0 = w * 32;               // this wave's j-range
    const int k0 = l * 4;                // this lane's k-quad

    // ---- A preload: Areg[jj] = A[j0+jj][k0..k0+3], 32 coalesced b128 loads
    float4 Areg[32];
#pragma unroll
    for (int jj = 0; jj < 32; ++jj)
        Areg[jj] = *(const float4*)&A[(size_t)(j0 + jj) * K + k0];

    // ---- reduce partials over 125 chunks: float4 loads, 8 c-groups ----
    {
        const int k4 = t & 63;           // float4 index within a k-row
        const int cg = t >> 6;           // chunk-group 0..7 (== w)
        const float4* p4 = (const float4*)partials;
        float4 m4 = make_float4(0.f, 0.f, 0.f, 0.f);
        for (int c = cg; c < NC; c += 8) {           // ~16 independent 16B loads
            float4 v = p4[((size_t)c * BATCH + b) * (K / 4) + k4];
            m4.x = fmaxf(m4.x, v.x);
            m4.y = fmaxf(m4.y, v.y);
            m4.z = fmaxf(m4.z, v.z);
            m4.w = fmaxf(m4.w, v.w);
        }
        red4[cg][k4] = m4;
    }
    if (t < HID) {
        int ci = cell_idx[b];
        ce_red[t] = cell_emb[ci * HID + t] * W2[t];
    }
    __syncthreads();

    float Smreg = 0.f;                   // S[k] for combine-thread k = t
    const float* red = (const float*)red4;
    if (t < K) {
        float s = red[t];
#pragma unroll
        for (int j = 1; j < 8; ++j) s = fmaxf(s, red[j * K + t]);
        Smreg = s;
        ((float*)zb4)[t] = s;            // zb[0] = Z0 = S
    }
    if (t == 0) {
        float s = b2[0];
        for (int h = 0; h < HID; ++h) s += ce_red[h];
        ce_dot[b] = s;
    }
    __syncthreads();

    // ---- 10 propagation steps ----
    for (int s = 0; s < STEPS; ++s) {
        const float4* zc = zb4[s & 1] + w * 8;       // wave-uniform base
        float4 acc = make_float4(0.f, 0.f, 0.f, 0.f);
#pragma unroll
        for (int q = 0; q < 8; ++q) {
            float4 z4 = zc[q];                       // same-address b128 broadcast
            float4 A0 = Areg[4 * q + 0], A1 = Areg[4 * q + 1];
            float4 A2 = Areg[4 * q + 2], A3 = Areg[4 * q + 3];
            acc.x = fmaf(z4.x, A0.x, acc.x); acc.x = fmaf(z4.y, A1.x, acc.x);
            acc.x = fmaf(z4.z, A2.x, acc.x); acc.x = fmaf(z4.w, A3.x, acc.x);
            acc.y = fmaf(z4.x, A0.y, acc.y); acc.y = fmaf(z4.y, A1.y, acc.y);
            acc.y = fmaf(z4.z, A2.y, acc.y); acc.y = fmaf(z4.w, A3.y, acc.y);
            acc.z = fmaf(z4.x, A0.z, acc.z); acc.z = fmaf(z4.y, A1.z, acc.z);
            acc.z = fmaf(z4.z, A2.z, acc.z); acc.z = fmaf(z4.w, A3.z, acc.z);
            acc.w = fmaf(z4.x, A0.w, acc.w); acc.w = fmaf(z4.y, A1.w, acc.w);
            acc.w = fmaf(z4.z, A2.w, acc.w); acc.w = fmaf(z4.w, A3.w, acc.w);
        }
        red4[w][l] = acc;                // wave partial, contiguous b128 write
        __syncthreads();
        if (t < K) {
            float sum = red[t]         + red[K + t]     + red[2 * K + t]
                      + red[3 * K + t] + red[4 * K + t] + red[5 * K + t]
                      + red[6 * K + t] + red[7 * K + t];
            ((float*)zb4)[((s + 1) & 1) * K + t] = fmaf(0.9f, sum, 0.1f * Smreg);
        }
        __syncthreads();
    }
    // after 10 (even) steps the result sits in zb[0]
    if (t < K) Zfin[b * K + t] = ((const float*)zb4)[t];
}

// ---------------------------------------------------------------------------
// Kernel C: z_gene = Z @ M^T fused with the per-element MLP (unchanged from
// round 3 — measured good). 158 blocks = 79 gene-groups x 2 batch-halves;
// register double-buffered M prefetch hides L3 latency under FMAs.
// ---------------------------------------------------------------------------
__global__ __launch_bounds__(256)
void final_kernel(const float* __restrict__ ctl,
                  const float* __restrict__ t_in,
                  const float* __restrict__ Z,
                  const float* __restrict__ M,
                  const float* __restrict__ W1,
                  const float* __restrict__ b1,
                  const float* __restrict__ W2,
                  const float* __restrict__ ce_dot,
                  float* __restrict__ out) {
    __shared__ float4 zl[8 * (K / 4)];       // 8 KB: this half's 8 Z rows
    __shared__ float4 wpack[HID];            // (W1row0, W1row1, W1row2, b1)
    __shared__ float  w2l[HID];
    __shared__ float  cel[8];

    const int tid = threadIdx.x;
    const int bh  = blockIdx.x & 1;          // batch half: batches bh*8..+8
    const int gb  = blockIdx.x >> 1;         // gene group 0..78
    const int b0  = bh * 8;

    const float4* Z4 = (const float4*)Z + (size_t)b0 * (K / 4);
    for (int i = tid; i < 8 * (K / 4); i += 256) zl[i] = Z4[i];
    if (tid < HID) {
        wpack[tid] = make_float4(W1[tid], W1[HID + tid], W1[2 * HID + tid], b1[tid]);
        w2l[tid] = W2[tid];
    }
    if (tid < 8) cel[tid] = ce_dot[b0 + tid];
    __syncthreads();

    const int gl = tid & 63;
    const int bg = tid >> 6;             // 0..3 -> 2 batches each (wave-uniform)
    const int g  = gb * 64 + gl;
    if (g >= G) return;                  // no barriers after this point

    const float4* M4 = (const float4*)(M + (size_t)g * K);

    float acc0 = 0.f, acc1 = 0.f;
    float4 mc[8];
#pragma unroll
    for (int u = 0; u < 8; ++u) mc[u] = M4[u];          // chunk 0 in flight

#pragma unroll
    for (int kc = 0; kc < 8; ++kc) {
        float4 mn[8];
        if (kc < 7) {
#pragma unroll
            for (int u = 0; u < 8; ++u) mn[u] = M4[(kc + 1) * 8 + u];  // prefetch
        }
#pragma unroll
        for (int u = 0; u < 8; ++u) {
            const int k4 = kc * 8 + u;
            float4 m4 = mc[u];
            float4 za = zl[(bg * 2 + 0) * (K / 4) + k4];   // broadcast read
            float4 zc = zl[(bg * 2 + 1) * (K / 4) + k4];   // broadcast read
            acc0 = fmaf(m4.x, za.x, acc0);
            acc0 = fmaf(m4.y, za.y, acc0);
            acc0 = fmaf(m4.z, za.z, acc0);
            acc0 = fmaf(m4.w, za.w, acc0);
            acc1 = fmaf(m4.x, zc.x, acc1);
            acc1 = fmaf(m4.y, zc.y, acc1);
            acc1 = fmaf(m4.z, zc.z, acc1);
            acc1 = fmaf(m4.w, zc.w, acc1);
        }
        if (kc < 7) {
#pragma unroll
            for (int u = 0; u < 8; ++u) mc[u] = mn[u];  // SSA rename, no movs
        }
    }

    const int ba = b0 + bg * 2;
    const int bb = ba + 1;
    float cva = ctl[ba * G + g], cvb = ctl[bb * G + g];   // coalesced across gl
    float tva = t_in[ba * G + g], tvb = t_in[bb * G + g];
    float ya  = cel[bg * 2],      yb  = cel[bg * 2 + 1];
#pragma unroll 8
    for (int h = 0; h < HID; ++h) {
        float4 w = wpack[h];           // broadcast
        float w2h = w2l[h];
        float pa = fmaf(cva, w.x, fmaf(tva, w.y, fmaf(acc0, w.z, w.w)));
        pa = fmaxf(pa, 0.f);
        ya = fmaf(pa, w2h, ya);
        float pb = fmaf(cvb, w.x, fmaf(tvb, w.y, fmaf(acc1, w.z, w.w)));
        pb = fmaxf(pb, 0.f);
        yb = fmaf(pb, w2h, yb);
    }
    out[ba * G + g] = ya;
    out[bb * G + g] = yb;
}

// ---------------------------------------------------------------------------
extern "C" void kernel_launch(void* const* d_in, const int* in_sizes, int n_in,
                              void* d_out, int out_size, void* d_ws, size_t ws_size,
                              hipStream_t stream) {
    const float* ctl      = (const float*)d_in[0];
    const float* tgt      = (const float*)d_in[1];
    const int*   cell_idx = (const int*)d_in[2];
    // d_in[3] = drug_fp (unused by the reference output)
    const float* M        = (const float*)d_in[4];
    const float* A        = (const float*)d_in[5];
    const float* W1       = (const float*)d_in[6];
    const float* b1       = (const float*)d_in[7];
    const float* cell_emb = (const float*)d_in[8];
    const float* W2       = (const float*)d_in[9];
    const float* b2       = (const float*)d_in[10];
    float* out = (float*)d_out;

    float* partials = (float*)d_ws;                     // 125*16*256 f32 (2 MB)
    float* Zfin  = partials + (size_t)NC * BATCH * K;   // 16*256
    float* ce    = Zfin + BATCH * K;                    // 16
    float* awarm = ce + BATCH;                          // 64 (garbage dump)

    maxpool_kernel<<<NC * 2, 256, 0, stream>>>(tgt, M, A, partials, awarm);
    appnp_fused<<<BATCH, 512, 0, stream>>>(partials, A, cell_idx, cell_emb,
                                           W2, b2, Zfin, ce);
    final_kernel<<<79 * 2, 256, 0, stream>>>(ctl, tgt, Zfin, M, W1, b1,
                                             W2, ce, out);
}